// Round 11
// baseline (75.106 us; speedup 1.0000x reference)
//
#include <hip/hip_runtime.h>
#include <math.h>

#define SMALL_EPS 1e-8f

typedef float     f4 __attribute__((ext_vector_type(4)));
typedef int       i4 __attribute__((ext_vector_type(4)));
typedef _Float16  h8 __attribute__((ext_vector_type(8)));   // 16 B pose record

__device__ __forceinline__ float frcp(float x) { return __builtin_amdgcn_rcpf(x); }
__device__ __forceinline__ float frsq(float x) { return __builtin_amdgcn_rsqf(x); }

// NT load for GATHERS only: random 16B records never share a 64B line, so
// bypassing L1 loses no coalescing and keeps them out of the L1 miss queue.
__device__ __forceinline__ h8 ldnt_pose(const h8* p) {
    return __builtin_nontemporal_load(p);
}

// max abs err ~7e-5 rad (Abramowitz-Stegun 4.4.45)
__device__ __forceinline__ float fast_acos(float x) {
    float ax = fabsf(x);
    float r = sqrtf(fmaxf(1.0f - ax, 0.0f)) *
        (1.5707288f + ax * (-0.2121144f + ax * (0.0742610f + ax * (-0.0187293f))));
    return (x < 0.0f) ? (3.14159265358979f - r) : r;
}

// exp map to (unit quaternion, translation):  xi[6] -> q[4], t[3]
__device__ __forceinline__ void exp_se3_quat(const float xi[6], float q[4], float t[3]) {
    const float x = xi[0], y = xi[1], z = xi[2];
    const float t2 = x * x + y * y + z * z;
    const float t2s = fmaxf(t2, 1e-12f);
    const float rth = frsq(t2s);          // 1/sqrt
    const float th  = t2s * rth;          // sqrt
    const float rt2 = rth * rth;          // 1/t2s
    float sh, ch;
    __sincosf(0.5f * th, &sh, &ch);
    const bool small = t2 < SMALL_EPS;
    const float k = small ? 0.5f - t2 * (1.0f / 48.0f) : sh * rth;  // sin(th/2)/th
    q[0] = ch; q[1] = k * x; q[2] = k * y; q[3] = k * z;
    const float sin_th = 2.0f * sh * ch;
    const float cos_th = 1.0f - 2.0f * sh * sh;
    const float B = small ? 0.5f - t2 * (1.0f / 24.0f)            : (1.0f - cos_th) * rt2;
    const float C = small ? (1.0f / 6.0f) - t2 * (1.0f / 120.0f)  : (th - sin_th) * rt2 * rth;
    const float v0 = xi[3], v1 = xi[4], v2 = xi[5];
    const float c0 = y * v2 - z * v1;
    const float c1 = z * v0 - x * v2;
    const float c2 = x * v1 - y * v0;
    const float d0 = y * c2 - z * c1;
    const float d1 = z * c0 - x * c2;
    const float d2 = x * c1 - y * c0;
    t[0] = v0 + B * c0 + C * d0;
    t[1] = v1 + B * c1 + C * d1;
    t[2] = v2 + B * c2 + C * d2;
}

// o = conj(a) * b
__device__ __forceinline__ void qconj_mul(const float a[4], const float b[4], float o[4]) {
    o[0] = a[0] * b[0] + a[1] * b[1] + a[2] * b[2] + a[3] * b[3];
    o[1] = a[0] * b[1] - b[0] * a[1] - (a[2] * b[3] - a[3] * b[2]);
    o[2] = a[0] * b[2] - b[0] * a[2] - (a[3] * b[1] - a[1] * b[3]);
    o[3] = a[0] * b[3] - b[0] * a[3] - (a[1] * b[2] - a[2] * b[1]);
}

// o = R(q)^T v
__device__ __forceinline__ void qconj_rot(const float q[4], const float v[3], float o[3]) {
    const float ux = -q[1], uy = -q[2], uz = -q[3];
    const float tx = 2.0f * (uy * v[2] - uz * v[1]);
    const float ty = 2.0f * (uz * v[0] - ux * v[2]);
    const float tz = 2.0f * (ux * v[1] - uy * v[0]);
    o[0] = v[0] + q[0] * tx + (uy * tz - uz * ty);
    o[1] = v[1] + q[0] * ty + (uz * tx - ux * tz);
    o[2] = v[2] + q[0] * tz + (ux * ty - uy * tx);
}

// log map from (q, t) -> sum of squares of xi
__device__ __forceinline__ float log_se3_sq_quat(const float q[4], const float t[3]) {
    const float cth = fminf(fmaxf(2.0f * q[0] * q[0] - 1.0f, -1.0f), 1.0f);
    const float th = fast_acos(cth);
    const float t2 = th * th;
    const float t2s = fmaxf(t2, 1e-12f);
    const float rt2s = frcp(t2s);
    const bool small = t2 < SMALL_EPS;
    const float sth = sqrtf(fmaxf(1.0f - cth * cth, 0.0f));
    const float fac = small ? 0.5f + t2 * (1.0f / 12.0f) : 0.5f * th * frcp(sth);
    const float g = 4.0f * q[0] * fac;
    const float wx = g * q[1], wy = g * q[2], wz = g * q[3];
    const float A = small ? 1.0f : sth * frcp(th);
    const float B = small ? 0.5f : (1.0f - cth) * rt2s;
    const float coef = small ? (1.0f / 12.0f) + t2 * (1.0f / 720.0f)
                             : (1.0f - 0.5f * A * frcp(B)) * rt2s;
    const float c0 = wy * t[2] - wz * t[1];
    const float c1 = wz * t[0] - wx * t[2];
    const float c2 = wx * t[1] - wy * t[0];
    const float d0 = wy * c2 - wz * c1;
    const float d1 = wz * c0 - wx * c2;
    const float d2 = wx * c1 - wy * c0;
    const float vx = t[0] - 0.5f * c0 + coef * d0;
    const float vy = t[1] - 0.5f * c1 + coef * d1;
    const float vz = t[2] - 0.5f * c2 + coef * d2;
    return wx * wx + wy * wy + wz * wz + vx * vx + vy * vy + vz * vz;
}

__device__ __forceinline__ void load6(const float* __restrict__ p, float xi[6]) {
    const float2* p2 = reinterpret_cast<const float2*>(p);
    float2 a = p2[0], b = p2[1], c = p2[2];
    xi[0] = a.x; xi[1] = a.y; xi[2] = b.x; xi[3] = b.y; xi[4] = c.x; xi[5] = c.y;
}

__device__ __forceinline__ void unpack_pose(const h8 rec, float q[4], float t[3]) {
    q[0] = (float)rec[0]; q[1] = (float)rec[1]; q[2] = (float)rec[2]; q[3] = (float)rec[3];
    t[0] = (float)rec[4]; t[1] = (float)rec[5]; t[2] = (float)rec[6];
}

// residual given both poses (quat+t) and precomputed measurement (qm,tm)
__device__ __forceinline__ float edge_residual_pre(
    const float qi[4], const float ti[3],
    const float qj[4], const float tj[3],
    const float qm[4], const float tm[3])
{
    float qc[4], tc[3];
    const float dvec[3] = { tj[0] - ti[0], tj[1] - ti[1], tj[2] - ti[2] };
    qconj_mul(qi, qj, qc);
    qconj_rot(qi, dvec, tc);
    float qr[4], tr[3];
    const float evec[3] = { tc[0] - tm[0], tc[1] - tm[1], tc[2] - tm[2] };
    qconj_mul(qm, qc, qr);
    qconj_rot(qm, evec, tr);
    return log_se3_sq_quat(qr, tr);
}

// ---------- kernel 1: exp all poses into 16B f16 records ----------
__global__ __launch_bounds__(256) void exp_poses_kernel(
    const float* __restrict__ poses, h8* __restrict__ table, int N)
{
    const int i = blockIdx.x * blockDim.x + threadIdx.x;
    if (i >= N) return;
    float xi[6];
    load6(poses + 6 * (size_t)i, xi);
    float q[4], t[3];
    exp_se3_quat(xi, q, t);
    h8 rec;
    rec[0] = (_Float16)q[0]; rec[1] = (_Float16)q[1];
    rec[2] = (_Float16)q[2]; rec[3] = (_Float16)q[3];
    rec[4] = (_Float16)t[0]; rec[5] = (_Float16)t[1];
    rec[6] = (_Float16)t[2]; rec[7] = (_Float16)0.0f;
    table[i] = rec;
}

// ---------- kernel 2: 4 edges/thread; NT gathers, cached stream ----------
__global__ __launch_bounds__(256) void edge_loss_kernel(
    const h8* __restrict__ table,
    const int* __restrict__ edges,
    const float* __restrict__ meas,
    float* __restrict__ partials,
    int E)
{
    const int t = blockIdx.x * blockDim.x + threadIdx.x;
    const int e0 = 4 * t;
    float loss = 0.0f;

    if (e0 + 3 < E) {
        // 2 x int4: all 4 edge pairs (32 B, coalesced, cached)
        const i4* ep = reinterpret_cast<const i4*>(edges + 8 * (size_t)t);
        const i4 edA = ep[0];
        const i4 edB = ep[1];

        // 6 x float4: all 4 measurements (96 B, coalesced, cached)
        const f4* mp = reinterpret_cast<const f4*>(meas + 24 * (size_t)t);
        const f4 m0 = mp[0], m1 = mp[1], m2 = mp[2];
        const f4 m3 = mp[3], m4 = mp[4], m5 = mp[5];

        // 8 independent pose gathers, L1-bypassing (no line sharing to lose)
        const h8 p0 = ldnt_pose(table + edA.x);
        const h8 p1 = ldnt_pose(table + edA.y);
        const h8 p2 = ldnt_pose(table + edA.z);
        const h8 p3 = ldnt_pose(table + edA.w);
        const h8 p4 = ldnt_pose(table + edB.x);
        const h8 p5 = ldnt_pose(table + edB.y);
        const h8 p6 = ldnt_pose(table + edB.z);
        const h8 p7 = ldnt_pose(table + edB.w);

        // measurement exp maps execute under gather latency (independent)
        const float xm0[6] = { m0.x, m0.y, m0.z, m0.w, m1.x, m1.y };
        const float xm1[6] = { m1.z, m1.w, m2.x, m2.y, m2.z, m2.w };
        const float xm2[6] = { m3.x, m3.y, m3.z, m3.w, m4.x, m4.y };
        const float xm3[6] = { m4.z, m4.w, m5.x, m5.y, m5.z, m5.w };
        float qm0[4], tm0[3], qm1[4], tm1[3], qm2[4], tm2[3], qm3[4], tm3[3];
        exp_se3_quat(xm0, qm0, tm0);
        exp_se3_quat(xm1, qm1, tm1);
        exp_se3_quat(xm2, qm2, tm2);
        exp_se3_quat(xm3, qm3, tm3);

        float qa[4], ta[3], qb[4], tb[3];
        unpack_pose(p0, qa, ta); unpack_pose(p1, qb, tb);
        loss  = edge_residual_pre(qa, ta, qb, tb, qm0, tm0);
        unpack_pose(p2, qa, ta); unpack_pose(p3, qb, tb);
        loss += edge_residual_pre(qa, ta, qb, tb, qm1, tm1);
        unpack_pose(p4, qa, ta); unpack_pose(p5, qb, tb);
        loss += edge_residual_pre(qa, ta, qb, tb, qm2, tm2);
        unpack_pose(p6, qa, ta); unpack_pose(p7, qb, tb);
        loss += edge_residual_pre(qa, ta, qb, tb, qm3, tm3);
    } else if (e0 < E) {
        for (int e = e0; e < E; ++e) {
            const int i = edges[2 * e];
            const int j = edges[2 * e + 1];
            float xm[6];
            load6(meas + 6 * (size_t)e, xm);
            float qm[4], tm[3];
            exp_se3_quat(xm, qm, tm);
            float qi[4], ti[3], qj[4], tj[3];
            unpack_pose(table[i], qi, ti);
            unpack_pose(table[j], qj, tj);
            loss += edge_residual_pre(qi, ti, qj, tj, qm, tm);
        }
    }

    #pragma unroll
    for (int off = 32; off > 0; off >>= 1)
        loss += __shfl_down(loss, off);

    __shared__ float sdata[4];
    const int lane = threadIdx.x & 63;
    const int wid = threadIdx.x >> 6;
    if (lane == 0) sdata[wid] = loss;
    __syncthreads();
    if (threadIdx.x == 0)
        partials[blockIdx.x] = (sdata[0] + sdata[1]) + (sdata[2] + sdata[3]);
}

// ---------- kernel 3: final reduce (1024 threads, deterministic order) ----------
__global__ __launch_bounds__(1024) void reduce_kernel(
    const float* __restrict__ partials, int n, float* __restrict__ out, float invE)
{
    float s = 0.0f;
    for (int i = threadIdx.x; i < n; i += 1024) s += partials[i];
    #pragma unroll
    for (int off = 32; off > 0; off >>= 1) s += __shfl_down(s, off);
    __shared__ float sd[16];
    const int lane = threadIdx.x & 63;
    const int wid = threadIdx.x >> 6;
    if (lane == 0) sd[wid] = s;
    __syncthreads();
    if (threadIdx.x == 0) {
        float tot = 0.0f;
        #pragma unroll
        for (int w = 0; w < 16; ++w) tot += sd[w];
        out[0] = tot * invE;
    }
}

// ---------- fallback (ws too small): zero + fused, atomic, full f32 ----------
__global__ void zero_out_kernel(float* out) { out[0] = 0.0f; }

__global__ __launch_bounds__(256) void fused_kernel(
    const float* __restrict__ poses,
    const int* __restrict__ edges,
    const float* __restrict__ meas,
    float* __restrict__ out,
    int N, int E, float invE)
{
    const int e = blockIdx.x * blockDim.x + threadIdx.x;
    float loss = 0.0f;
    if (e < E) {
        const int i = edges[2 * e];
        const int j = edges[2 * e + 1];
        float xi_i[6], xi_j[6], xi_m[6];
        load6(poses + 6 * (size_t)i, xi_i);
        load6(poses + 6 * (size_t)j, xi_j);
        load6(meas + 6 * (size_t)e, xi_m);
        float qi[4], ti[3], qj[4], tj[3], qm[4], tm[3];
        exp_se3_quat(xi_i, qi, ti);
        exp_se3_quat(xi_j, qj, tj);
        exp_se3_quat(xi_m, qm, tm);
        loss = edge_residual_pre(qi, ti, qj, tj, qm, tm);
    }
    #pragma unroll
    for (int off = 32; off > 0; off >>= 1) loss += __shfl_down(loss, off);
    __shared__ float sdata[4];
    const int lane = threadIdx.x & 63;
    const int wid = threadIdx.x >> 6;
    if (lane == 0) sdata[wid] = loss;
    __syncthreads();
    if (threadIdx.x == 0)
        atomicAdd(out, ((sdata[0] + sdata[1]) + (sdata[2] + sdata[3])) * invE);
}

extern "C" void kernel_launch(void* const* d_in, const int* in_sizes, int n_in,
                              void* d_out, int out_size, void* d_ws, size_t ws_size,
                              hipStream_t stream) {
    const float* poses = (const float*)d_in[0];
    const int*   edges = (const int*)d_in[1];
    const float* meas  = (const float*)d_in[2];
    float* out = (float*)d_out;

    const int N = in_sizes[0] / 6;
    const int E = in_sizes[2] / 6;
    const float invE = 1.0f / (float)E;

    const int block = 256;
    const int nthreads = (E + 3) / 4;                    // 4 edges per thread
    const int grid_e = (nthreads + block - 1) / block;
    const size_t table_bytes = (size_t)N * 16;           // 16 B / pose (8 x f16)
    const size_t need = table_bytes + (size_t)grid_e * sizeof(float);

    if (ws_size >= need) {
        h8* table = (h8*)d_ws;
        float* partials = (float*)((char*)d_ws + table_bytes);
        const int grid_n = (N + block - 1) / block;
        exp_poses_kernel<<<grid_n, block, 0, stream>>>(poses, table, N);
        edge_loss_kernel<<<grid_e, block, 0, stream>>>(table, edges, meas, partials, E);
        reduce_kernel<<<1, 1024, 0, stream>>>(partials, grid_e, out, invE);
    } else {
        zero_out_kernel<<<1, 1, 0, stream>>>(out);
        const int grid_f = (E + block - 1) / block;
        fused_kernel<<<grid_f, block, 0, stream>>>(poses, edges, meas, out, N, E, invE);
    }
}

// Round 12
// 39.553 us; speedup vs baseline: 1.8989x; 1.8989x over previous
//
#include <hip/hip_runtime.h>
#include <math.h>

#define SMALL_EPS 1e-8f

typedef float     f4 __attribute__((ext_vector_type(4)));
typedef int       i4 __attribute__((ext_vector_type(4)));
typedef _Float16  h8 __attribute__((ext_vector_type(8)));   // 16 B pose record

__device__ __forceinline__ float frcp(float x) { return __builtin_amdgcn_rcpf(x); }
__device__ __forceinline__ float frsq(float x) { return __builtin_amdgcn_rsqf(x); }

// max abs err ~7e-5 rad (Abramowitz-Stegun 4.4.45)
__device__ __forceinline__ float fast_acos(float x) {
    float ax = fabsf(x);
    float r = sqrtf(fmaxf(1.0f - ax, 0.0f)) *
        (1.5707288f + ax * (-0.2121144f + ax * (0.0742610f + ax * (-0.0187293f))));
    return (x < 0.0f) ? (3.14159265358979f - r) : r;
}

// exp map to (unit quaternion, translation):  xi[6] -> q[4], t[3]
__device__ __forceinline__ void exp_se3_quat(const float xi[6], float q[4], float t[3]) {
    const float x = xi[0], y = xi[1], z = xi[2];
    const float t2 = x * x + y * y + z * z;
    const float t2s = fmaxf(t2, 1e-12f);
    const float rth = frsq(t2s);          // 1/sqrt
    const float th  = t2s * rth;          // sqrt
    const float rt2 = rth * rth;          // 1/t2s
    float sh, ch;
    __sincosf(0.5f * th, &sh, &ch);
    const bool small = t2 < SMALL_EPS;
    const float k = small ? 0.5f - t2 * (1.0f / 48.0f) : sh * rth;  // sin(th/2)/th
    q[0] = ch; q[1] = k * x; q[2] = k * y; q[3] = k * z;
    const float sin_th = 2.0f * sh * ch;
    const float cos_th = 1.0f - 2.0f * sh * sh;
    const float B = small ? 0.5f - t2 * (1.0f / 24.0f)            : (1.0f - cos_th) * rt2;
    const float C = small ? (1.0f / 6.0f) - t2 * (1.0f / 120.0f)  : (th - sin_th) * rt2 * rth;
    const float v0 = xi[3], v1 = xi[4], v2 = xi[5];
    const float c0 = y * v2 - z * v1;
    const float c1 = z * v0 - x * v2;
    const float c2 = x * v1 - y * v0;
    const float d0 = y * c2 - z * c1;
    const float d1 = z * c0 - x * c2;
    const float d2 = x * c1 - y * c0;
    t[0] = v0 + B * c0 + C * d0;
    t[1] = v1 + B * c1 + C * d1;
    t[2] = v2 + B * c2 + C * d2;
}

// o = conj(a) * b
__device__ __forceinline__ void qconj_mul(const float a[4], const float b[4], float o[4]) {
    o[0] = a[0] * b[0] + a[1] * b[1] + a[2] * b[2] + a[3] * b[3];
    o[1] = a[0] * b[1] - b[0] * a[1] - (a[2] * b[3] - a[3] * b[2]);
    o[2] = a[0] * b[2] - b[0] * a[2] - (a[3] * b[1] - a[1] * b[3]);
    o[3] = a[0] * b[3] - b[0] * a[3] - (a[1] * b[2] - a[2] * b[1]);
}

// o = R(q)^T v
__device__ __forceinline__ void qconj_rot(const float q[4], const float v[3], float o[3]) {
    const float ux = -q[1], uy = -q[2], uz = -q[3];
    const float tx = 2.0f * (uy * v[2] - uz * v[1]);
    const float ty = 2.0f * (uz * v[0] - ux * v[2]);
    const float tz = 2.0f * (ux * v[1] - uy * v[0]);
    o[0] = v[0] + q[0] * tx + (uy * tz - uz * ty);
    o[1] = v[1] + q[0] * ty + (uz * tx - ux * tz);
    o[2] = v[2] + q[0] * tz + (ux * ty - uy * tx);
}

// log map from (q, t) -> sum of squares of xi
__device__ __forceinline__ float log_se3_sq_quat(const float q[4], const float t[3]) {
    const float cth = fminf(fmaxf(2.0f * q[0] * q[0] - 1.0f, -1.0f), 1.0f);
    const float th = fast_acos(cth);
    const float t2 = th * th;
    const float t2s = fmaxf(t2, 1e-12f);
    const float rt2s = frcp(t2s);
    const bool small = t2 < SMALL_EPS;
    const float sth = sqrtf(fmaxf(1.0f - cth * cth, 0.0f));
    const float fac = small ? 0.5f + t2 * (1.0f / 12.0f) : 0.5f * th * frcp(sth);
    const float g = 4.0f * q[0] * fac;
    const float wx = g * q[1], wy = g * q[2], wz = g * q[3];
    const float A = small ? 1.0f : sth * frcp(th);
    const float B = small ? 0.5f : (1.0f - cth) * rt2s;
    const float coef = small ? (1.0f / 12.0f) + t2 * (1.0f / 720.0f)
                             : (1.0f - 0.5f * A * frcp(B)) * rt2s;
    const float c0 = wy * t[2] - wz * t[1];
    const float c1 = wz * t[0] - wx * t[2];
    const float c2 = wx * t[1] - wy * t[0];
    const float d0 = wy * c2 - wz * c1;
    const float d1 = wz * c0 - wx * c2;
    const float d2 = wx * c1 - wy * c0;
    const float vx = t[0] - 0.5f * c0 + coef * d0;
    const float vy = t[1] - 0.5f * c1 + coef * d1;
    const float vz = t[2] - 0.5f * c2 + coef * d2;
    return wx * wx + wy * wy + wz * wz + vx * vx + vy * vy + vz * vz;
}

__device__ __forceinline__ void load6(const float* __restrict__ p, float xi[6]) {
    const float2* p2 = reinterpret_cast<const float2*>(p);
    float2 a = p2[0], b = p2[1], c = p2[2];
    xi[0] = a.x; xi[1] = a.y; xi[2] = b.x; xi[3] = b.y; xi[4] = c.x; xi[5] = c.y;
}

__device__ __forceinline__ void unpack_pose(const h8 rec, float q[4], float t[3]) {
    q[0] = (float)rec[0]; q[1] = (float)rec[1]; q[2] = (float)rec[2]; q[3] = (float)rec[3];
    t[0] = (float)rec[4]; t[1] = (float)rec[5]; t[2] = (float)rec[6];
}

// residual given both poses (quat+t) and precomputed measurement (qm,tm)
__device__ __forceinline__ float edge_residual_pre(
    const float qi[4], const float ti[3],
    const float qj[4], const float tj[3],
    const float qm[4], const float tm[3])
{
    float qc[4], tc[3];
    const float dvec[3] = { tj[0] - ti[0], tj[1] - ti[1], tj[2] - ti[2] };
    qconj_mul(qi, qj, qc);
    qconj_rot(qi, dvec, tc);
    float qr[4], tr[3];
    const float evec[3] = { tc[0] - tm[0], tc[1] - tm[1], tc[2] - tm[2] };
    qconj_mul(qm, qc, qr);
    qconj_rot(qm, evec, tr);
    return log_se3_sq_quat(qr, tr);
}

// ---------- kernel 1: exp all poses into 16B f16 records ----------
__global__ __launch_bounds__(256) void exp_poses_kernel(
    const float* __restrict__ poses, h8* __restrict__ table, int N)
{
    const int i = blockIdx.x * blockDim.x + threadIdx.x;
    if (i >= N) return;
    float xi[6];
    load6(poses + 6 * (size_t)i, xi);
    float q[4], t[3];
    exp_se3_quat(xi, q, t);
    h8 rec;
    rec[0] = (_Float16)q[0]; rec[1] = (_Float16)q[1];
    rec[2] = (_Float16)q[2]; rec[3] = (_Float16)q[3];
    rec[4] = (_Float16)t[0]; rec[5] = (_Float16)t[1];
    rec[6] = (_Float16)t[2]; rec[7] = (_Float16)0.0f;
    table[i] = rec;
}

// ---------- kernel 2: 4 edges/thread, all loads batched (plain, cached) ----------
__global__ __launch_bounds__(256) void edge_loss_kernel(
    const h8* __restrict__ table,
    const int* __restrict__ edges,
    const float* __restrict__ meas,
    float* __restrict__ partials,
    int E)
{
    const int t = blockIdx.x * blockDim.x + threadIdx.x;
    const int e0 = 4 * t;
    float loss = 0.0f;

    if (e0 + 3 < E) {
        // 2 x int4: all 4 edge pairs (32 B, coalesced)
        const i4* ep = reinterpret_cast<const i4*>(edges + 8 * (size_t)t);
        const i4 edA = ep[0];
        const i4 edB = ep[1];

        // 6 x float4: all 4 measurements (96 B, coalesced)
        const f4* mp = reinterpret_cast<const f4*>(meas + 24 * (size_t)t);
        const f4 m0 = mp[0], m1 = mp[1], m2 = mp[2];
        const f4 m3 = mp[3], m4 = mp[4], m5 = mp[5];

        // 8 independent pose gathers, 1 x 16 B request each — all in flight together.
        // Plain cached loads: table (1.6 MB) must stay L2-resident (nt evicts it — r11).
        const h8 p0 = table[edA.x];
        const h8 p1 = table[edA.y];
        const h8 p2 = table[edA.z];
        const h8 p3 = table[edA.w];
        const h8 p4 = table[edB.x];
        const h8 p5 = table[edB.y];
        const h8 p6 = table[edB.z];
        const h8 p7 = table[edB.w];

        // measurement exp maps execute under gather latency (independent)
        const float xm0[6] = { m0.x, m0.y, m0.z, m0.w, m1.x, m1.y };
        const float xm1[6] = { m1.z, m1.w, m2.x, m2.y, m2.z, m2.w };
        const float xm2[6] = { m3.x, m3.y, m3.z, m3.w, m4.x, m4.y };
        const float xm3[6] = { m4.z, m4.w, m5.x, m5.y, m5.z, m5.w };
        float qm0[4], tm0[3], qm1[4], tm1[3], qm2[4], tm2[3], qm3[4], tm3[3];
        exp_se3_quat(xm0, qm0, tm0);
        exp_se3_quat(xm1, qm1, tm1);
        exp_se3_quat(xm2, qm2, tm2);
        exp_se3_quat(xm3, qm3, tm3);

        float qa[4], ta[3], qb[4], tb[3];
        unpack_pose(p0, qa, ta); unpack_pose(p1, qb, tb);
        loss  = edge_residual_pre(qa, ta, qb, tb, qm0, tm0);
        unpack_pose(p2, qa, ta); unpack_pose(p3, qb, tb);
        loss += edge_residual_pre(qa, ta, qb, tb, qm1, tm1);
        unpack_pose(p4, qa, ta); unpack_pose(p5, qb, tb);
        loss += edge_residual_pre(qa, ta, qb, tb, qm2, tm2);
        unpack_pose(p6, qa, ta); unpack_pose(p7, qb, tb);
        loss += edge_residual_pre(qa, ta, qb, tb, qm3, tm3);
    } else if (e0 < E) {
        for (int e = e0; e < E; ++e) {
            const int i = edges[2 * e];
            const int j = edges[2 * e + 1];
            float xm[6];
            load6(meas + 6 * (size_t)e, xm);
            float qm[4], tm[3];
            exp_se3_quat(xm, qm, tm);
            float qi[4], ti[3], qj[4], tj[3];
            unpack_pose(table[i], qi, ti);
            unpack_pose(table[j], qj, tj);
            loss += edge_residual_pre(qi, ti, qj, tj, qm, tm);
        }
    }

    #pragma unroll
    for (int off = 32; off > 0; off >>= 1)
        loss += __shfl_down(loss, off);

    __shared__ float sdata[4];
    const int lane = threadIdx.x & 63;
    const int wid = threadIdx.x >> 6;
    if (lane == 0) sdata[wid] = loss;
    __syncthreads();
    if (threadIdx.x == 0)
        partials[blockIdx.x] = (sdata[0] + sdata[1]) + (sdata[2] + sdata[3]);
}

// ---------- kernel 3: final reduce (1024 threads, deterministic order) ----------
__global__ __launch_bounds__(1024) void reduce_kernel(
    const float* __restrict__ partials, int n, float* __restrict__ out, float invE)
{
    float s = 0.0f;
    for (int i = threadIdx.x; i < n; i += 1024) s += partials[i];
    #pragma unroll
    for (int off = 32; off > 0; off >>= 1) s += __shfl_down(s, off);
    __shared__ float sd[16];
    const int lane = threadIdx.x & 63;
    const int wid = threadIdx.x >> 6;
    if (lane == 0) sd[wid] = s;
    __syncthreads();
    if (threadIdx.x == 0) {
        float tot = 0.0f;
        #pragma unroll
        for (int w = 0; w < 16; ++w) tot += sd[w];
        out[0] = tot * invE;
    }
}

// ---------- fallback (ws too small): zero + fused, atomic, full f32 ----------
__global__ void zero_out_kernel(float* out) { out[0] = 0.0f; }

__global__ __launch_bounds__(256) void fused_kernel(
    const float* __restrict__ poses,
    const int* __restrict__ edges,
    const float* __restrict__ meas,
    float* __restrict__ out,
    int N, int E, float invE)
{
    const int e = blockIdx.x * blockDim.x + threadIdx.x;
    float loss = 0.0f;
    if (e < E) {
        const int i = edges[2 * e];
        const int j = edges[2 * e + 1];
        float xi_i[6], xi_j[6], xi_m[6];
        load6(poses + 6 * (size_t)i, xi_i);
        load6(poses + 6 * (size_t)j, xi_j);
        load6(meas + 6 * (size_t)e, xi_m);
        float qi[4], ti[3], qj[4], tj[3], qm[4], tm[3];
        exp_se3_quat(xi_i, qi, ti);
        exp_se3_quat(xi_j, qj, tj);
        exp_se3_quat(xi_m, qm, tm);
        loss = edge_residual_pre(qi, ti, qj, tj, qm, tm);
    }
    #pragma unroll
    for (int off = 32; off > 0; off >>= 1) loss += __shfl_down(loss, off);
    __shared__ float sdata[4];
    const int lane = threadIdx.x & 63;
    const int wid = threadIdx.x >> 6;
    if (lane == 0) sdata[wid] = loss;
    __syncthreads();
    if (threadIdx.x == 0)
        atomicAdd(out, ((sdata[0] + sdata[1]) + (sdata[2] + sdata[3])) * invE);
}

extern "C" void kernel_launch(void* const* d_in, const int* in_sizes, int n_in,
                              void* d_out, int out_size, void* d_ws, size_t ws_size,
                              hipStream_t stream) {
    const float* poses = (const float*)d_in[0];
    const int*   edges = (const int*)d_in[1];
    const float* meas  = (const float*)d_in[2];
    float* out = (float*)d_out;

    const int N = in_sizes[0] / 6;
    const int E = in_sizes[2] / 6;
    const float invE = 1.0f / (float)E;

    const int block = 256;
    const int nthreads = (E + 3) / 4;                    // 4 edges per thread
    const int grid_e = (nthreads + block - 1) / block;
    const size_t table_bytes = (size_t)N * 16;           // 16 B / pose (8 x f16)
    const size_t need = table_bytes + (size_t)grid_e * sizeof(float);

    if (ws_size >= need) {
        h8* table = (h8*)d_ws;
        float* partials = (float*)((char*)d_ws + table_bytes);
        const int grid_n = (N + block - 1) / block;
        exp_poses_kernel<<<grid_n, block, 0, stream>>>(poses, table, N);
        edge_loss_kernel<<<grid_e, block, 0, stream>>>(table, edges, meas, partials, E);
        reduce_kernel<<<1, 1024, 0, stream>>>(partials, grid_e, out, invE);
    } else {
        zero_out_kernel<<<1, 1, 0, stream>>>(out);
        const int grid_f = (E + block - 1) / block;
        fused_kernel<<<grid_f, block, 0, stream>>>(poses, edges, meas, out, N, E, invE);
    }
}